// Round 1
// baseline (310.062 us; speedup 1.0000x reference)
//
#include <hip/hip_runtime.h>
#include <hip/hip_bf16.h>
#include <math.h>

#define TT 4096
#define EE 8
#define DD 1024
#define HH 1024
#define CAP 4096

typedef __attribute__((ext_vector_type(8))) short bf16x8;
typedef __attribute__((ext_vector_type(4))) float f32x4;

// async global->LDS, 16B per lane; LDS dest is wave-uniform base + lane*16
#define GLL16(gp, lp)                                                                   \
    __builtin_amdgcn_global_load_lds((__attribute__((address_space(1))) void*)(gp),     \
                                     (__attribute__((address_space(3))) void*)(lp),     \
                                     16, 0, 0)

// ---------------- workspace layout (bytes) ----------------
static const size_t OFF_XB     = 0;                         // bf16 [4096][1024]  8 MB
static const size_t OFF_W1T    = 8u * 1024 * 1024;          // bf16 [8][H][D]    16 MB
static const size_t OFF_W2T    = 24u * 1024 * 1024;         // bf16 [8][D][H]    16 MB
static const size_t OFF_ABUF   = 40u * 1024 * 1024;         // bf16 [8192][1024] 16 MB
static const size_t OFF_OBUF   = 56u * 1024 * 1024;         // f32  [8192][1024] 32 MB
static const size_t OFF_ROWMAP = 88u * 1024 * 1024;         // int  [8][4096]   128 KB
static const size_t OFF_GATES  = OFF_ROWMAP + 8 * CAP * 4;  // f32  [8192]       32 KB
static const size_t OFF_COUNTS = OFF_GATES + 8192 * 4;      // int  [8]

// ---------------- gating: logits, softmax, top-2, bucket; also x -> bf16 ----------------
__global__ __launch_bounds__(64) void gate_kernel(
    const float* __restrict__ x, const float* __restrict__ wg,
    __hip_bfloat16* __restrict__ xb, int* __restrict__ rowmap,
    float* __restrict__ gates, int* __restrict__ counts)
{
    const int t = blockIdx.x;
    const int lane = threadIdx.x;
    const float* xr = x + (size_t)t * DD;
    __hip_bfloat16* xbr = xb + (size_t)t * DD;

    float acc[EE];
#pragma unroll
    for (int e = 0; e < EE; ++e) acc[e] = 0.f;

#pragma unroll 4
    for (int j = 0; j < DD / 64; ++j) {
        int d = lane + 64 * j;
        float xv = xr[d];
        xbr[d] = __float2bfloat16(xv);
        const float* wr = wg + (size_t)d * EE;
#pragma unroll
        for (int e = 0; e < EE; ++e) acc[e] = fmaf(xv, wr[e], acc[e]);
    }
#pragma unroll
    for (int off = 32; off > 0; off >>= 1) {
#pragma unroll
        for (int e = 0; e < EE; ++e) acc[e] += __shfl_xor(acc[e], off, 64);
    }
    if (lane == 0) {
        float mx = acc[0];
#pragma unroll
        for (int e = 1; e < EE; ++e) mx = fmaxf(mx, acc[e]);
        float p[EE];
        float s = 0.f;
#pragma unroll
        for (int e = 0; e < EE; ++e) { p[e] = expf(acc[e] - mx); s += p[e]; }
        int i0 = 0;
#pragma unroll
        for (int e = 1; e < EE; ++e) if (acc[e] > acc[i0]) i0 = e;
        int i1 = (i0 == 0) ? 1 : 0;
#pragma unroll
        for (int e = 0; e < EE; ++e) {
            if (e != i0 && acc[e] > acc[i1]) i1 = e;
        }
        float v0 = p[i0] / s, v1 = p[i1] / s;        // top-2 softmax probs
        float den = v0 + v1 + 1e-6f;                 // reference renorm
        gates[t * 2 + 0] = v0 / den;
        gates[t * 2 + 1] = v1 / den;
        int pos0 = atomicAdd(&counts[i0], 1);
        rowmap[i0 * CAP + pos0] = t * 2 + 0;
        int pos1 = atomicAdd(&counts[i1], 1);
        rowmap[i1 * CAP + pos1] = t * 2 + 1;
    }
}

// ---------------- weight transpose + fp32->bf16 (B needs K-contiguous layout) ----------------
__global__ __launch_bounds__(256) void transpose_cvt(
    const float* __restrict__ w1, const float* __restrict__ w2,
    __hip_bfloat16* __restrict__ w1t, __hip_bfloat16* __restrict__ w2t)
{
    __shared__ float tile[32][33];
    const int z = blockIdx.z;
    const float* src = (z < EE ? w1 : w2) + (size_t)(z & 7) * DD * HH;
    __hip_bfloat16* dst = (z < EE ? w1t : w2t) + (size_t)(z & 7) * DD * HH;
    const int bx = blockIdx.x * 32, by = blockIdx.y * 32;
    const int tx = threadIdx.x & 31, ty = threadIdx.x >> 5;
#pragma unroll
    for (int i = 0; i < 4; ++i)
        tile[ty + 8 * i][tx] = src[(size_t)(by + ty + 8 * i) * 1024 + bx + tx];
    __syncthreads();
#pragma unroll
    for (int i = 0; i < 4; ++i)
        dst[(size_t)(bx + ty + 8 * i) * 1024 + by + tx] = __float2bfloat16(tile[tx][ty + 8 * i]);
}

// ---------------- grouped GEMM (m97 structure: 128x128 tile, BK=32, global_load_lds) -------
// LAYER==1: A = xb gathered by token; out = gelu(C + b1) -> bf16 a_buf[(t,k) slot]
// LAYER==2: A = a_buf gathered by slot; out = (C + b2) * gate -> f32 o_buf[(t,k) slot]
template <int LAYER>
__global__ __launch_bounds__(256) void moe_gemm(
    const __hip_bfloat16* __restrict__ Abase,
    const __hip_bfloat16* __restrict__ Bbase,   // [E][N=1024][K=1024], K contiguous
    const float* __restrict__ bias,             // [E][1024]
    const int* __restrict__ rowmap,
    const int* __restrict__ counts,
    const float* __restrict__ gates,
    void* __restrict__ OutP)
{
    const int e = blockIdx.z;
    const int cnt = counts[e];
    const int m0 = blockIdx.y * 128;
    if (m0 >= cnt) return;
    const int n0 = blockIdx.x * 128;
    const int tid = threadIdx.x;
    const int lane = tid & 63;
    const int wave = tid >> 6;
    const int wm = (wave >> 1) * 64;   // wave's 64x64 quadrant
    const int wn = (wave & 1) * 64;
    const int lrow = lane & 15;
    const int quad = lane >> 4;

    __shared__ __hip_bfloat16 As[128 * 32];   // [m][k], k contiguous, 8 KB
    __shared__ __hip_bfloat16 Bs[128 * 32];   // [n][k], k contiguous, 8 KB

    // staging source rows (2 rows per thread: tid/4 and tid/4+64), gathered via rowmap
    const int ar0 = m0 + (tid >> 2);
    const int ar1 = ar0 + 64;
    const int e0 = rowmap[e * CAP + (ar0 < cnt ? ar0 : 0)];
    const int e1 = rowmap[e * CAP + (ar1 < cnt ? ar1 : 0)];
    const size_t src0 = (size_t)(LAYER == 1 ? (e0 >> 1) : e0);
    const size_t src1 = (size_t)(LAYER == 1 ? (e1 >> 1) : e1);
    const __hip_bfloat16* gA0 = Abase + src0 * DD + (tid & 3) * 8;
    const __hip_bfloat16* gA1 = Abase + src1 * DD + (tid & 3) * 8;
    const __hip_bfloat16* Bexp = Bbase + (size_t)e * DD * HH;
    const __hip_bfloat16* gB0 = Bexp + (size_t)(n0 + (tid >> 2)) * DD + (tid & 3) * 8;
    const __hip_bfloat16* gB1 = gB0 + (size_t)64 * DD;

    // wave-uniform LDS staging bases; lane l writes base + l*16
    char* ldsA0 = (char*)As + wave * 1024;
    char* ldsA1 = (char*)As + 4096 + wave * 1024;
    char* ldsB0 = (char*)Bs + wave * 1024;
    char* ldsB1 = (char*)Bs + 4096 + wave * 1024;

    f32x4 acc[4][4];
#pragma unroll
    for (int i = 0; i < 4; ++i)
#pragma unroll
        for (int j = 0; j < 4; ++j) acc[i][j] = (f32x4){0.f, 0.f, 0.f, 0.f};

    const bf16x8* Av = (const bf16x8*)As;
    const bf16x8* Bv = (const bf16x8*)Bs;

    for (int kt = 0; kt < DD / 32; ++kt) {
        const int ko = kt * 32;
        GLL16(gA0 + ko, ldsA0);
        GLL16(gA1 + ko, ldsA1);
        GLL16(gB0 + ko, ldsB0);
        GLL16(gB1 + ko, ldsB1);
        __syncthreads();   // compiler drains vmcnt before s_barrier

        bf16x8 af[4], bfr[4];
#pragma unroll
        for (int i = 0; i < 4; ++i) {
            af[i]  = Av[(wm + i * 16 + lrow) * 4 + quad];   // A[m][k0+quad*8 ..+7]
            bfr[i] = Bv[(wn + i * 16 + lrow) * 4 + quad];   // B[k][n] via [n][k] LDS
        }
#pragma unroll
        for (int mi = 0; mi < 4; ++mi)
#pragma unroll
            for (int ni = 0; ni < 4; ++ni)
                acc[mi][ni] = __builtin_amdgcn_mfma_f32_16x16x32_bf16(
                    af[mi], bfr[ni], acc[mi][ni], 0, 0, 0);
        __syncthreads();
    }

    // epilogue: C/D layout col = lane&15, row = quad*4 + reg (m89/m91 verified)
    if (LAYER == 1) {
        __hip_bfloat16* abuf = (__hip_bfloat16*)OutP;
#pragma unroll
        for (int mi = 0; mi < 4; ++mi) {
#pragma unroll
            for (int r = 0; r < 4; ++r) {
                const int mrow = wm + mi * 16 + quad * 4 + r;
                const int gm = m0 + mrow;
                if (gm < cnt) {
                    const int ent = rowmap[e * CAP + gm];
                    __hip_bfloat16* orow = abuf + (size_t)ent * HH + n0 + wn + lrow;
#pragma unroll
                    for (int ni = 0; ni < 4; ++ni) {
                        float v = acc[mi][ni][r] + bias[e * HH + n0 + wn + ni * 16 + lrow];
                        v = 0.5f * v * (1.f + erff(v * 0.70710678118654752f));  // exact GELU
                        orow[ni * 16] = __float2bfloat16(v);
                    }
                }
            }
        }
    } else {
        float* obuf = (float*)OutP;
#pragma unroll
        for (int mi = 0; mi < 4; ++mi) {
#pragma unroll
            for (int r = 0; r < 4; ++r) {
                const int mrow = wm + mi * 16 + quad * 4 + r;
                const int gm = m0 + mrow;
                if (gm < cnt) {
                    const int ent = rowmap[e * CAP + gm];
                    const float g = gates[ent];
                    float* orow = obuf + (size_t)ent * DD + n0 + wn + lrow;
#pragma unroll
                    for (int ni = 0; ni < 4; ++ni) {
                        float v = acc[mi][ni][r] + bias[e * DD + n0 + wn + ni * 16 + lrow];
                        orow[ni * 16] = v * g;
                    }
                }
            }
        }
    }
}

// ---------------- combine: y[t] = o[t,0] + o[t,1] ----------------
__global__ __launch_bounds__(256) void combine_kernel(
    const float* __restrict__ obuf, float* __restrict__ y)
{
    const size_t i = (size_t)blockIdx.x * 256 + threadIdx.x;  // over TT*DD/4 float4s
    const size_t t = i >> 8;          // 256 float4 per token row
    const size_t c = i & 255;
    const float4* o0 = (const float4*)(obuf + t * 2 * DD);
    float4 a = o0[c];
    float4 b = o0[256 + c];
    float4 r;
    r.x = a.x + b.x; r.y = a.y + b.y; r.z = a.z + b.z; r.w = a.w + b.w;
    ((float4*)y)[i] = r;
}

extern "C" void kernel_launch(void* const* d_in, const int* in_sizes, int n_in,
                              void* d_out, int out_size, void* d_ws, size_t ws_size,
                              hipStream_t stream)
{
    const float* x  = (const float*)d_in[0];
    const float* w1 = (const float*)d_in[1];
    const float* b1 = (const float*)d_in[2];
    const float* w2 = (const float*)d_in[3];
    const float* b2 = (const float*)d_in[4];
    const float* wg = (const float*)d_in[5];
    float* y = (float*)d_out;

    char* ws = (char*)d_ws;
    __hip_bfloat16* xb   = (__hip_bfloat16*)(ws + OFF_XB);
    __hip_bfloat16* w1t  = (__hip_bfloat16*)(ws + OFF_W1T);
    __hip_bfloat16* w2t  = (__hip_bfloat16*)(ws + OFF_W2T);
    __hip_bfloat16* abuf = (__hip_bfloat16*)(ws + OFF_ABUF);
    float* obuf  = (float*)(ws + OFF_OBUF);
    int*   rowmap = (int*)(ws + OFF_ROWMAP);
    float* gates  = (float*)(ws + OFF_GATES);
    int*   counts = (int*)(ws + OFF_COUNTS);

    hipMemsetAsync(counts, 0, EE * sizeof(int), stream);
    gate_kernel<<<TT, 64, 0, stream>>>(x, wg, xb, rowmap, gates, counts);
    transpose_cvt<<<dim3(32, 32, 16), 256, 0, stream>>>(w1, w2, w1t, w2t);
    moe_gemm<1><<<dim3(HH / 128, CAP / 128, EE), 256, 0, stream>>>(
        xb, w1t, b1, rowmap, counts, gates, (void*)abuf);
    moe_gemm<2><<<dim3(DD / 128, CAP / 128, EE), 256, 0, stream>>>(
        abuf, w2t, b2, rowmap, counts, gates, (void*)obuf);
    combine_kernel<<<TT * DD / 4 / 256, 256, 0, stream>>>(obuf, y);
}

// Round 2
// 241.234 us; speedup vs baseline: 1.2853x; 1.2853x over previous
//
#include <hip/hip_runtime.h>
#include <hip/hip_bf16.h>
#include <math.h>

#define TT 4096
#define EE 8
#define DD 1024
#define HH 1024
#define CAP 4096

typedef __attribute__((ext_vector_type(8))) short bf16x8;
typedef __attribute__((ext_vector_type(4))) float f32x4;

// async global->LDS, 16B per lane; LDS dest is wave-uniform base + lane*16
#define GLL16(gp, lp)                                                                   \
    __builtin_amdgcn_global_load_lds((__attribute__((address_space(1))) void*)(gp),     \
                                     (__attribute__((address_space(3))) void*)(lp),     \
                                     16, 0, 0)

// ---------------- workspace layout (bytes) ----------------
static const size_t OFF_XB     = 0;                         // bf16 [4096][1024]  8 MB
static const size_t OFF_W1T    = 8u * 1024 * 1024;          // bf16 [8][H][D]    16 MB
static const size_t OFF_W2T    = 24u * 1024 * 1024;         // bf16 [8][D][H]    16 MB
static const size_t OFF_ABUF   = 40u * 1024 * 1024;         // bf16 [8192][1024] 16 MB
static const size_t OFF_OBUF   = 56u * 1024 * 1024;         // f32  [8192][1024] 32 MB
static const size_t OFF_ROWMAP = 88u * 1024 * 1024;         // int  [8][4096]   128 KB
static const size_t OFF_GATES  = OFF_ROWMAP + 8 * CAP * 4;  // f32  [8192]       32 KB
static const size_t OFF_COUNTS = OFF_GATES + 8192 * 4;      // int  [8]
static const size_t OFF_PICKS  = OFF_COUNTS + 256;          // int  [4096]       16 KB

// ---------------- gating (no atomics): logits, softmax, top-2; x -> bf16 ----------------
// 256 blocks x 256 threads; wave w handles tokens blockIdx*16 + w*4 .. +3
__global__ __launch_bounds__(256) void gate_compute(
    const float* __restrict__ x, const float* __restrict__ wg,
    __hip_bfloat16* __restrict__ xb, int* __restrict__ picks,
    float* __restrict__ gates)
{
    const int lane = threadIdx.x & 63;
    const int wave = threadIdx.x >> 6;
    const int tbase = blockIdx.x * 16 + wave * 4;

    for (int i = 0; i < 4; ++i) {
        const int t = tbase + i;
        const float4* xr = (const float4*)(x + (size_t)t * DD);
        ushort4* xbr = (ushort4*)(xb + (size_t)t * DD);

        float acc[EE];
#pragma unroll
        for (int e = 0; e < EE; ++e) acc[e] = 0.f;

#pragma unroll
        for (int c = 0; c < 4; ++c) {
            const int v4 = lane + 64 * c;     // float4 index within the row
            float4 xv = xr[v4];
            // bf16 convert + 8B packed store
            __hip_bfloat16 h0 = __float2bfloat16(xv.x);
            __hip_bfloat16 h1 = __float2bfloat16(xv.y);
            __hip_bfloat16 h2 = __float2bfloat16(xv.z);
            __hip_bfloat16 h3 = __float2bfloat16(xv.w);
            ushort4 s;
            s.x = *(unsigned short*)&h0; s.y = *(unsigned short*)&h1;
            s.z = *(unsigned short*)&h2; s.w = *(unsigned short*)&h3;
            xbr[v4] = s;
            // wg rows d..d+3, each row = 8 contiguous floats = 2 float4
            const float4* wrow = (const float4*)(wg + (size_t)(4 * v4) * EE);
            const float xs[4] = {xv.x, xv.y, xv.z, xv.w};
#pragma unroll
            for (int q = 0; q < 4; ++q) {
                float4 w0 = wrow[q * 2];
                float4 w1v = wrow[q * 2 + 1];
                acc[0] = fmaf(xs[q], w0.x, acc[0]);
                acc[1] = fmaf(xs[q], w0.y, acc[1]);
                acc[2] = fmaf(xs[q], w0.z, acc[2]);
                acc[3] = fmaf(xs[q], w0.w, acc[3]);
                acc[4] = fmaf(xs[q], w1v.x, acc[4]);
                acc[5] = fmaf(xs[q], w1v.y, acc[5]);
                acc[6] = fmaf(xs[q], w1v.z, acc[6]);
                acc[7] = fmaf(xs[q], w1v.w, acc[7]);
            }
        }
#pragma unroll
        for (int off = 32; off > 0; off >>= 1) {
#pragma unroll
            for (int e = 0; e < EE; ++e) acc[e] += __shfl_xor(acc[e], off, 64);
        }
        if (lane == 0) {
            float mx = acc[0];
#pragma unroll
            for (int e = 1; e < EE; ++e) mx = fmaxf(mx, acc[e]);
            float p[EE];
            float s = 0.f;
#pragma unroll
            for (int e = 0; e < EE; ++e) { p[e] = expf(acc[e] - mx); s += p[e]; }
            int i0 = 0;
#pragma unroll
            for (int e = 1; e < EE; ++e) if (acc[e] > acc[i0]) i0 = e;
            int i1 = (i0 == 0) ? 1 : 0;
#pragma unroll
            for (int e = 0; e < EE; ++e) {
                if (e != i0 && acc[e] > acc[i1]) i1 = e;
            }
            float v0 = p[i0] / s, v1 = p[i1] / s;   // top-2 softmax probs
            float den = v0 + v1 + 1e-6f;            // reference renorm
            gates[t * 2 + 0] = v0 / den;
            gates[t * 2 + 1] = v1 / den;
            picks[t] = i0 | (i1 << 4);
        }
    }
}

// ---------------- bucket build (deterministic, no global atomics) ----------------
// one block per expert; block-wide prefix-sum compaction of picks into rowmap
__global__ __launch_bounds__(256) void bucket_build(
    const int* __restrict__ picks, int* __restrict__ rowmap, int* __restrict__ counts)
{
    const int e = blockIdx.x;
    const int tid = threadIdx.x;
    const int lane = tid & 63;
    const int wave = tid >> 6;
    __shared__ int wsum[4];

    int runtot = 0;
    for (int tb = 0; tb < TT; tb += 256) {
        const int t = tb + tid;
        const int p = picks[t];
        const int m0 = ((p & 15) == e) ? 1 : 0;
        const int m1 = (((p >> 4) & 15) == e) ? 1 : 0;
        const int c = m0 + m1;
        // wave inclusive scan of c
        int incl = c;
#pragma unroll
        for (int off = 1; off < 64; off <<= 1) {
            int v = __shfl_up(incl, off, 64);
            if (lane >= off) incl += v;
        }
        if (lane == 63) wsum[wave] = incl;
        __syncthreads();
        int wbase = 0;
#pragma unroll
        for (int w = 0; w < 4; ++w) wbase += (w < wave) ? wsum[w] : 0;
        int slot = runtot + wbase + incl - c;
        if (m0) { rowmap[e * CAP + slot] = t * 2; slot += 1; }
        if (m1) { rowmap[e * CAP + slot] = t * 2 + 1; }
        runtot += wsum[0] + wsum[1] + wsum[2] + wsum[3];   // uniform across block
        __syncthreads();   // protect wsum for next iteration
    }
    if (tid == 0) counts[e] = runtot;
}

// ---------------- weight transpose + fp32->bf16 (B needs K-contiguous layout) ----------------
__global__ __launch_bounds__(256) void transpose_cvt(
    const float* __restrict__ w1, const float* __restrict__ w2,
    __hip_bfloat16* __restrict__ w1t, __hip_bfloat16* __restrict__ w2t)
{
    __shared__ float tile[32][33];
    const int z = blockIdx.z;
    const float* src = (z < EE ? w1 : w2) + (size_t)(z & 7) * DD * HH;
    __hip_bfloat16* dst = (z < EE ? w1t : w2t) + (size_t)(z & 7) * DD * HH;
    const int bx = blockIdx.x * 32, by = blockIdx.y * 32;
    const int tx = threadIdx.x & 31, ty = threadIdx.x >> 5;
#pragma unroll
    for (int i = 0; i < 4; ++i)
        tile[ty + 8 * i][tx] = src[(size_t)(by + ty + 8 * i) * 1024 + bx + tx];
    __syncthreads();
#pragma unroll
    for (int i = 0; i < 4; ++i)
        dst[(size_t)(bx + ty + 8 * i) * 1024 + by + tx] = __float2bfloat16(tile[tx][ty + 8 * i]);
}

// ---------------- grouped GEMM (m97 structure: 128x128 tile, BK=32, global_load_lds) -------
// LAYER==1: A = xb gathered by token; out = gelu(C + b1) -> bf16 a_buf[(t,k) slot]
// LAYER==2: A = a_buf gathered by slot; out = (C + b2) * gate -> f32 o_buf[(t,k) slot]
template <int LAYER>
__global__ __launch_bounds__(256) void moe_gemm(
    const __hip_bfloat16* __restrict__ Abase,
    const __hip_bfloat16* __restrict__ Bbase,   // [E][N=1024][K=1024], K contiguous
    const float* __restrict__ bias,             // [E][1024]
    const int* __restrict__ rowmap,
    const int* __restrict__ counts,
    const float* __restrict__ gates,
    void* __restrict__ OutP)
{
    const int e = blockIdx.z;
    const int cnt = counts[e];
    const int m0 = blockIdx.y * 128;
    if (m0 >= cnt) return;
    const int n0 = blockIdx.x * 128;
    const int tid = threadIdx.x;
    const int lane = tid & 63;
    const int wave = tid >> 6;
    const int wm = (wave >> 1) * 64;   // wave's 64x64 quadrant
    const int wn = (wave & 1) * 64;
    const int lrow = lane & 15;
    const int quad = lane >> 4;

    __shared__ __hip_bfloat16 As[128 * 32];   // [m][k], k contiguous, 8 KB
    __shared__ __hip_bfloat16 Bs[128 * 32];   // [n][k], k contiguous, 8 KB

    // staging source rows (2 rows per thread: tid/4 and tid/4+64), gathered via rowmap
    const int ar0 = m0 + (tid >> 2);
    const int ar1 = ar0 + 64;
    const int e0 = rowmap[e * CAP + (ar0 < cnt ? ar0 : 0)];
    const int e1 = rowmap[e * CAP + (ar1 < cnt ? ar1 : 0)];
    const size_t src0 = (size_t)(LAYER == 1 ? (e0 >> 1) : e0);
    const size_t src1 = (size_t)(LAYER == 1 ? (e1 >> 1) : e1);
    const __hip_bfloat16* gA0 = Abase + src0 * DD + (tid & 3) * 8;
    const __hip_bfloat16* gA1 = Abase + src1 * DD + (tid & 3) * 8;
    const __hip_bfloat16* Bexp = Bbase + (size_t)e * DD * HH;
    const __hip_bfloat16* gB0 = Bexp + (size_t)(n0 + (tid >> 2)) * DD + (tid & 3) * 8;
    const __hip_bfloat16* gB1 = gB0 + (size_t)64 * DD;

    // wave-uniform LDS staging bases; lane l writes base + l*16
    char* ldsA0 = (char*)As + wave * 1024;
    char* ldsA1 = (char*)As + 4096 + wave * 1024;
    char* ldsB0 = (char*)Bs + wave * 1024;
    char* ldsB1 = (char*)Bs + 4096 + wave * 1024;

    f32x4 acc[4][4];
#pragma unroll
    for (int i = 0; i < 4; ++i)
#pragma unroll
        for (int j = 0; j < 4; ++j) acc[i][j] = (f32x4){0.f, 0.f, 0.f, 0.f};

    const bf16x8* Av = (const bf16x8*)As;
    const bf16x8* Bv = (const bf16x8*)Bs;

    for (int kt = 0; kt < DD / 32; ++kt) {
        const int ko = kt * 32;
        GLL16(gA0 + ko, ldsA0);
        GLL16(gA1 + ko, ldsA1);
        GLL16(gB0 + ko, ldsB0);
        GLL16(gB1 + ko, ldsB1);
        __syncthreads();   // compiler drains vmcnt before s_barrier

        bf16x8 af[4], bfr[4];
#pragma unroll
        for (int i = 0; i < 4; ++i) {
            af[i]  = Av[(wm + i * 16 + lrow) * 4 + quad];   // A[m][k0+quad*8 ..+7]
            bfr[i] = Bv[(wn + i * 16 + lrow) * 4 + quad];   // B[k][n] via [n][k] LDS
        }
#pragma unroll
        for (int mi = 0; mi < 4; ++mi)
#pragma unroll
            for (int ni = 0; ni < 4; ++ni)
                acc[mi][ni] = __builtin_amdgcn_mfma_f32_16x16x32_bf16(
                    af[mi], bfr[ni], acc[mi][ni], 0, 0, 0);
        __syncthreads();
    }

    // epilogue: C/D layout col = lane&15, row = quad*4 + reg (m89/m91 verified)
    if (LAYER == 1) {
        __hip_bfloat16* abuf = (__hip_bfloat16*)OutP;
#pragma unroll
        for (int mi = 0; mi < 4; ++mi) {
#pragma unroll
            for (int r = 0; r < 4; ++r) {
                const int mrow = wm + mi * 16 + quad * 4 + r;
                const int gm = m0 + mrow;
                if (gm < cnt) {
                    const int ent = rowmap[e * CAP + gm];
                    __hip_bfloat16* orow = abuf + (size_t)ent * HH + n0 + wn + lrow;
#pragma unroll
                    for (int ni = 0; ni < 4; ++ni) {
                        float v = acc[mi][ni][r] + bias[e * HH + n0 + wn + ni * 16 + lrow];
                        v = 0.5f * v * (1.f + erff(v * 0.70710678118654752f));  // exact GELU
                        orow[ni * 16] = __float2bfloat16(v);
                    }
                }
            }
        }
    } else {
        float* obuf = (float*)OutP;
#pragma unroll
        for (int mi = 0; mi < 4; ++mi) {
#pragma unroll
            for (int r = 0; r < 4; ++r) {
                const int mrow = wm + mi * 16 + quad * 4 + r;
                const int gm = m0 + mrow;
                if (gm < cnt) {
                    const int ent = rowmap[e * CAP + gm];
                    const float g = gates[ent];
                    float* orow = obuf + (size_t)ent * DD + n0 + wn + lrow;
#pragma unroll
                    for (int ni = 0; ni < 4; ++ni) {
                        float v = acc[mi][ni][r] + bias[e * DD + n0 + wn + ni * 16 + lrow];
                        orow[ni * 16] = v * g;
                    }
                }
            }
        }
    }
}

// ---------------- combine: y[t] = o[t,0] + o[t,1] ----------------
__global__ __launch_bounds__(256) void combine_kernel(
    const float* __restrict__ obuf, float* __restrict__ y)
{
    const size_t i = (size_t)blockIdx.x * 256 + threadIdx.x;  // over TT*DD/4 float4s
    const size_t t = i >> 8;          // 256 float4 per token row
    const size_t c = i & 255;
    const float4* o0 = (const float4*)(obuf + t * 2 * DD);
    float4 a = o0[c];
    float4 b = o0[256 + c];
    float4 r;
    r.x = a.x + b.x; r.y = a.y + b.y; r.z = a.z + b.z; r.w = a.w + b.w;
    ((float4*)y)[i] = r;
}

extern "C" void kernel_launch(void* const* d_in, const int* in_sizes, int n_in,
                              void* d_out, int out_size, void* d_ws, size_t ws_size,
                              hipStream_t stream)
{
    const float* x  = (const float*)d_in[0];
    const float* w1 = (const float*)d_in[1];
    const float* b1 = (const float*)d_in[2];
    const float* w2 = (const float*)d_in[3];
    const float* b2 = (const float*)d_in[4];
    const float* wg = (const float*)d_in[5];
    float* y = (float*)d_out;

    char* ws = (char*)d_ws;
    __hip_bfloat16* xb   = (__hip_bfloat16*)(ws + OFF_XB);
    __hip_bfloat16* w1t  = (__hip_bfloat16*)(ws + OFF_W1T);
    __hip_bfloat16* w2t  = (__hip_bfloat16*)(ws + OFF_W2T);
    __hip_bfloat16* abuf = (__hip_bfloat16*)(ws + OFF_ABUF);
    float* obuf  = (float*)(ws + OFF_OBUF);
    int*   rowmap = (int*)(ws + OFF_ROWMAP);
    float* gates  = (float*)(ws + OFF_GATES);
    int*   counts = (int*)(ws + OFF_COUNTS);
    int*   picks  = (int*)(ws + OFF_PICKS);

    gate_compute<<<TT / 16, 256, 0, stream>>>(x, wg, xb, picks, gates);
    bucket_build<<<EE, 256, 0, stream>>>(picks, rowmap, counts);
    transpose_cvt<<<dim3(32, 32, 16), 256, 0, stream>>>(w1, w2, w1t, w2t);
    moe_gemm<1><<<dim3(HH / 128, CAP / 128, EE), 256, 0, stream>>>(
        xb, w1t, b1, rowmap, counts, gates, (void*)abuf);
    moe_gemm<2><<<dim3(DD / 128, CAP / 128, EE), 256, 0, stream>>>(
        abuf, w2t, b2, rowmap, counts, gates, (void*)obuf);
    combine_kernel<<<TT * DD / 4 / 256, 256, 0, stream>>>(obuf, y);
}